// Round 7
// baseline (776.414 us; speedup 1.0000x reference)
//
#include <hip/hip_runtime.h>
#include <math.h>

// GAT 3-layer: N=50000 nodes, E=800000 edges (+N self loops), HEADS=2, HID=64.
// R7: XCD-sliced gather v2. H slice-major (8 slices x N x 16 cols; 3.2MB/slice
// fits one XCD's 4MiB L2; slice=blockIdx&7 pins it under round-robin dispatch
// — R5 measured FETCH 194->71MB with this mapping). Unlike R5, the gather
// keeps R4's ILP: per-edge (src,p) preloaded into registers lane-parallel,
// broadcast via shfl (no load-dependent addressing), 4 edges in flight per
// step x 16 cols. Softmax stats + per-edge p computed ONCE by stats_kernel
// (wave/dst), not replicated per slice.

__device__ __forceinline__ float lrelu(float v) { return v > 0.f ? v : 0.2f * v; }

__device__ __forceinline__ float wave_sum(float v) {
  for (int off = 32; off; off >>= 1) v += __shfl_xor(v, off, 64);
  return v;
}
__device__ __forceinline__ float wave_max(float v) {
  for (int off = 32; off; off >>= 1) v = fmaxf(v, __shfl_xor(v, off, 64));
  return v;
}

__global__ void init_kernel(int* __restrict__ deg, float* __restrict__ gsum,
                            int* __restrict__ gcnt, int n, int g) {
  int i = blockIdx.x * blockDim.x + threadIdx.x;
  if (i < n) deg[i] = 1;                 // self loop
  if (i < g) { gsum[i] = 0.f; gcnt[i] = 0; }
}

__global__ void count_kernel(const int* __restrict__ ei, int* __restrict__ deg, int e) {
  int i = blockIdx.x * blockDim.x + threadIdx.x;
  if (i < e) atomicAdd(&deg[ei[e + i]], 1);   // dst row of edge_index
}

// ---- hierarchical exclusive scan over deg[0..n) ----
__global__ void scan_blocks(const int* __restrict__ deg, int* __restrict__ row_ptr,
                            int* __restrict__ btot, int n) {
  __shared__ int sm[256];
  int i = blockIdx.x * 256 + threadIdx.x;
  int v = (i < n) ? deg[i] : 0;
  sm[threadIdx.x] = v;
  __syncthreads();
  for (int off = 1; off < 256; off <<= 1) {
    int t = (threadIdx.x >= off) ? sm[threadIdx.x - off] : 0;
    __syncthreads();
    sm[threadIdx.x] += t;
    __syncthreads();
  }
  if (i < n) row_ptr[i] = sm[threadIdx.x] - v;   // exclusive within block
  if (threadIdx.x == 255) btot[blockIdx.x] = sm[255];
}

__global__ void scan_totals(int* __restrict__ btot, int nb) {  // nb <= 256
  __shared__ int sm[256];
  int v = (threadIdx.x < nb) ? btot[threadIdx.x] : 0;
  sm[threadIdx.x] = v;
  __syncthreads();
  for (int off = 1; off < 256; off <<= 1) {
    int t = (threadIdx.x >= off) ? sm[threadIdx.x - off] : 0;
    __syncthreads();
    sm[threadIdx.x] += t;
    __syncthreads();
  }
  if (threadIdx.x < nb) btot[threadIdx.x] = sm[threadIdx.x] - v;  // exclusive
}

__global__ void scan_add(int* __restrict__ row_ptr, int* __restrict__ cursor,
                         const int* __restrict__ btot, int n, int total) {
  int i = blockIdx.x * 256 + threadIdx.x;
  if (i < n) {
    int v = row_ptr[i] + btot[blockIdx.x];
    row_ptr[i] = v;
    cursor[i] = v;
  }
  if (i == 0) row_ptr[n] = total;
}

__global__ void scatter_kernel(const int* __restrict__ ei, int* __restrict__ cursor,
                               int* __restrict__ csr_src, int n, int e) {
  int i = blockIdx.x * blockDim.x + threadIdx.x;
  if (i < n) {                               // self loop
    int p = atomicAdd(&cursor[i], 1);
    csr_src[p] = i;
  } else if (i < n + e) {
    int j = i - n;
    int s = ei[j];
    int d = ei[e + j];
    int p = atomicAdd(&cursor[d], 1);
    csr_src[p] = s;
  }
}

// Tiled gemm + fused attention reduce. H written SLICE-MAJOR:
// Hs[slice][node][16], slice = col/16 (slices 0-3 head0, 4-7 head1).
template <int K>
__global__ __launch_bounds__(256) void gemm_att(const float* __restrict__ X,
                                                const float* __restrict__ W,
                                                const float* __restrict__ asw,
                                                const float* __restrict__ adw,
                                                float* __restrict__ Hs,
                                                float* __restrict__ a_src,
                                                float* __restrict__ a_dst, int N) {
  __shared__ float Xs[64 * (K + 1)];
  int tid = threadIdx.x;
  int row0 = blockIdx.x * 64;

  for (int idx = tid; idx < 64 * K; idx += 256) {
    int r = idx / K;
    int k = idx - r * K;
    int gr = row0 + r;
    if (gr >= N) gr = N - 1;          // clamp pad rows (stores are guarded)
    Xs[r * (K + 1) + k] = X[(size_t)gr * K + k];
  }
  __syncthreads();

  int cgrp = tid & 31;
  int c0 = cgrp * 4;
  int rg = tid >> 5;
  const float* wp = W + c0;
  float acc[8][4] = {};

#pragma unroll 4
  for (int k = 0; k < K; ++k) {
    float4 w4 = *(const float4*)(wp + k * 128);
#pragma unroll
    for (int j = 0; j < 8; ++j) {
      float xv = Xs[(rg * 8 + j) * (K + 1) + k];
      acc[j][0] = fmaf(xv, w4.x, acc[j][0]);
      acc[j][1] = fmaf(xv, w4.y, acc[j][1]);
      acc[j][2] = fmaf(xv, w4.z, acc[j][2]);
      acc[j][3] = fmaf(xv, w4.w, acc[j][3]);
    }
  }

  int slice = c0 >> 4;
  int w16 = c0 & 15;
  float4 aw = *(const float4*)(asw + c0);
  float4 dw = *(const float4*)(adw + c0);
#pragma unroll
  for (int j = 0; j < 8; ++j) {
    int r = row0 + rg * 8 + j;
    float sp = acc[j][0] * aw.x + acc[j][1] * aw.y + acc[j][2] * aw.z + acc[j][3] * aw.w;
    float dp = acc[j][0] * dw.x + acc[j][1] * dw.y + acc[j][2] * dw.z + acc[j][3] * dw.w;
#pragma unroll
    for (int off = 1; off < 16; off <<= 1) {
      sp += __shfl_xor(sp, off, 64);
      dp += __shfl_xor(dp, off, 64);
    }
    if (r < N) {
      float4 v = make_float4(acc[j][0], acc[j][1], acc[j][2], acc[j][3]);
      *(float4*)(Hs + ((size_t)slice * N + r) * 16 + w16) = v;
      if ((cgrp & 15) == 0) {
        int head = cgrp >> 4;
        a_src[r * 2 + head] = sp;
        a_dst[r * 2 + head] = dp;
      }
    }
  }
}

// Wave per dst: exact softmax; writes per-edge p0/p1 (coalesced SoA) and
// per-dst 1/s. All random a_src gathers happen here, once.
__global__ __launch_bounds__(256) void stats_kernel(
    const float* __restrict__ a_src, const float* __restrict__ a_dst,
    const int* __restrict__ row_ptr, const int* __restrict__ csr,
    float* __restrict__ p0a, float* __restrict__ p1a,
    float2* __restrict__ invS, int N) {
  int wid = blockIdx.x * 4 + (threadIdx.x >> 6);
  if (wid >= N) return;
  int lane = threadIdx.x & 63;
  int beg = row_ptr[wid], end = row_ptr[wid + 1];
  float2 ad = ((const float2*)a_dst)[wid];

  if (end - beg <= 64) {
    int j = beg + lane;
    bool valid = j < end;
    int s = valid ? csr[j] : 0;
    float2 as = ((const float2*)a_src)[s];
    float e0 = valid ? lrelu(as.x + ad.x) : -1e30f;
    float e1 = valid ? lrelu(as.y + ad.y) : -1e30f;
    float m0 = wave_max(e0), m1 = wave_max(e1);
    float p0 = __expf(e0 - m0), p1 = __expf(e1 - m1);
    float s0 = wave_sum(valid ? p0 : 0.f);
    float s1 = wave_sum(valid ? p1 : 0.f);
    if (valid) { p0a[j] = p0; p1a[j] = p1; }
    if (lane == 0)
      invS[wid] = make_float2(1.f / fmaxf(s0, 1e-16f), 1.f / fmaxf(s1, 1e-16f));
  } else {
    float m0 = -1e30f, m1 = -1e30f, s0 = 0.f, s1 = 0.f;
    for (int base = beg; base < end; base += 64) {
      int j = base + lane;
      bool valid = j < end;
      int s = valid ? csr[j] : 0;
      float2 as = ((const float2*)a_src)[s];
      float e0 = valid ? lrelu(as.x + ad.x) : -1e30f;
      float e1 = valid ? lrelu(as.y + ad.y) : -1e30f;
      float nm0 = fmaxf(m0, wave_max(e0));
      float nm1 = fmaxf(m1, wave_max(e1));
      s0 = s0 * __expf(m0 - nm0) + wave_sum(valid ? __expf(e0 - nm0) : 0.f);
      s1 = s1 * __expf(m1 - nm1) + wave_sum(valid ? __expf(e1 - nm1) : 0.f);
      m0 = nm0; m1 = nm1;
    }
    for (int base = beg; base < end; base += 64) {
      int j = base + lane;
      bool valid = j < end;
      int s = valid ? csr[j] : 0;
      float2 as = ((const float2*)a_src)[s];
      if (valid) {
        p0a[j] = __expf(lrelu(as.x + ad.x) - m0);
        p1a[j] = __expf(lrelu(as.y + ad.y) - m1);
      }
    }
    if (lane == 0)
      invS[wid] = make_float2(1.f / fmaxf(s0, 1e-16f), 1.f / fmaxf(s1, 1e-16f));
  }
}

// XCD-sliced gather, ILP-preserving. Grid: 8 x ceil(N/4) blocks; block = 4
// waves, wave = one dst at slice = blockIdx&7. Lane = (t4, c16). Chunk
// preload: lane j holds (csr[beg+j], pH[beg+j]) — coalesced. Step loop:
// 4 edges in parallel (t4 dim), src/p broadcast via shfl (no memory dep in
// addressing), 16x4B coalesced L2-resident H load, 1 fma. Reduce over t4.
__global__ __launch_bounds__(256) void gather_slices2(
    const float* __restrict__ Hs, const int* __restrict__ row_ptr,
    const int* __restrict__ csr, const float* __restrict__ p0a,
    const float* __restrict__ p1a, float* __restrict__ Hagg, int N) {
  int slice = blockIdx.x & 7;
  int wid = (blockIdx.x >> 3) * 4 + (threadIdx.x >> 6);
  if (wid >= N) return;
  int lane = threadIdx.x & 63;
  int c16 = lane & 15;
  int t4 = lane >> 4;
  const float* __restrict__ pH = (slice < 4) ? p0a : p1a;
  const float* __restrict__ hs = Hs + (size_t)slice * N * 16 + c16;
  int beg = row_ptr[wid], end = row_ptr[wid + 1];
  float acc = 0.f;
  for (int base = beg; base < end; base += 64) {
    int j = base + lane;
    bool valid = j < end;
    int s = valid ? csr[j] : 0;
    float p = valid ? pH[j] : 0.f;
    int cnt = end - base;
    if (cnt > 64) cnt = 64;
    int steps = (cnt + 3) >> 2;
#pragma unroll 4
    for (int b = 0; b < steps; ++b) {
      int idx = b * 4 + t4;                 // <= 63 always
      int st = __shfl(s, idx, 64);
      float q = __shfl(p, idx, 64);         // 0 for idx >= cnt
      float h = hs[(size_t)st * 16];
      acc = fmaf(q, h, acc);
    }
  }
  acc += __shfl_xor(acc, 16, 64);
  acc += __shfl_xor(acc, 32, 64);
  if (t4 == 0) Hagg[(size_t)wid * 128 + slice * 16 + c16] = acc;
}

// inv + head-mean + bias + relu -> out [N,64]
__global__ void epilogue_kernel(const float* __restrict__ Hagg,
                                const float2* __restrict__ invS,
                                const float* __restrict__ bias,
                                float* __restrict__ out, int N) {
  int i = blockIdx.x * 256 + threadIdx.x;
  if (i >= N * 64) return;
  int dst = i >> 6, c = i & 63;
  float2 inv = invS[dst];
  float v = 0.5f * (Hagg[(size_t)dst * 128 + c] * inv.x +
                    Hagg[(size_t)dst * 128 + 64 + c] * inv.y) + bias[c];
  out[i] = v > 0.f ? v : 0.f;
}

// per-node dot with lin_w (linear commutes past the mean), atomic per-graph
__global__ void pool_kernel(const float* __restrict__ X, const float* __restrict__ lw,
                            const int* __restrict__ batch, float* __restrict__ gsum,
                            int* __restrict__ gcnt, int N) {
  int wid = blockIdx.x * (blockDim.x >> 6) + (threadIdx.x >> 6);
  if (wid >= N) return;
  int lane = threadIdx.x & 63;
  float v = X[(size_t)wid * 64 + lane] * lw[lane];
  v = wave_sum(v);
  if (lane == 0) {
    int g = batch[wid];
    atomicAdd(&gsum[g], v);
    atomicAdd(&gcnt[g], 1);
  }
}

__global__ void finalize_kernel(const float* __restrict__ gsum, const int* __restrict__ gcnt,
                                const float* __restrict__ lb, float* __restrict__ out, int G) {
  int g = blockIdx.x * blockDim.x + threadIdx.x;
  if (g < G) out[g] = gsum[g] / fmaxf((float)gcnt[g], 1.f) + lb[0];
}

extern "C" void kernel_launch(void* const* d_in, const int* in_sizes, int n_in,
                              void* d_out, int out_size, void* d_ws, size_t ws_size,
                              hipStream_t stream) {
  const float* x   = (const float*)d_in[0];
  const int* ei    = (const int*)d_in[1];
  const int* batch = (const int*)d_in[2];
  const float* W1  = (const float*)d_in[3];
  const float* as1 = (const float*)d_in[4];
  const float* ad1 = (const float*)d_in[5];
  const float* b1  = (const float*)d_in[6];
  const float* W2  = (const float*)d_in[7];
  const float* as2 = (const float*)d_in[8];
  const float* ad2 = (const float*)d_in[9];
  const float* b2  = (const float*)d_in[10];
  const float* W3  = (const float*)d_in[11];
  const float* as3 = (const float*)d_in[12];
  const float* ad3 = (const float*)d_in[13];
  const float* b3  = (const float*)d_in[14];
  const float* lw  = (const float*)d_in[15];
  const float* lb  = (const float*)d_in[16];
  float* out = (float*)d_out;

  const int N = in_sizes[0] / 128;   // 50000
  const int E = in_sizes[1] / 2;     // 800000
  const int ET = N + E;              // with self loops
  const int G = out_size;            // 2500
  const int NB = (N + 255) / 256;    // scan blocks (196 <= 256)

  char* p = (char*)d_ws;
  auto take = [&](size_t bytes) {
    char* r = p;
    p += (bytes + 255) & ~(size_t)255;
    return r;
  };
  int* deg      = (int*)take((size_t)N * 4);
  int* row_ptr  = (int*)take((size_t)(N + 1) * 4);
  int* cursor   = (int*)take((size_t)N * 4);
  int* btot     = (int*)take((size_t)NB * 4);
  int* csr      = (int*)take((size_t)ET * 4);
  float* Hs     = (float*)take((size_t)N * 128 * 4);  // slice-major
  float* Hagg   = (float*)take((size_t)N * 128 * 4);
  float* a_src  = (float*)take((size_t)N * 2 * 4);
  float* a_dst  = (float*)take((size_t)N * 2 * 4);
  float* p0a    = (float*)take((size_t)ET * 4);
  float* p1a    = (float*)take((size_t)ET * 4);
  float2* invS  = (float2*)take((size_t)N * 8);
  float* buf    = (float*)take((size_t)N * 64 * 4);
  float* gsum   = (float*)take((size_t)G * 4);
  int* gcnt     = (int*)take((size_t)G * 4);
  (void)ws_size; (void)n_in;

  // ---- CSR build (dst-sorted, with self loops) ----
  init_kernel<<<(N + 255) / 256, 256, 0, stream>>>(deg, gsum, gcnt, N, G);
  count_kernel<<<(E + 255) / 256, 256, 0, stream>>>(ei, deg, E);
  scan_blocks<<<NB, 256, 0, stream>>>(deg, row_ptr, btot, N);
  scan_totals<<<1, 256, 0, stream>>>(btot, NB);
  scan_add<<<NB, 256, 0, stream>>>(row_ptr, cursor, btot, N, ET);
  scatter_kernel<<<(ET + 255) / 256, 256, 0, stream>>>(ei, cursor, csr, N, E);

  const int gblk = (N + 63) / 64;
  const int wblk = (N + 3) / 4;
  const int sblk = 8 * ((N + 3) / 4);
  const int eblk = (N * 64 + 255) / 256;

  // ---- layer 1 (K=128) ----
  gemm_att<128><<<gblk, 256, 0, stream>>>(x, W1, as1, ad1, Hs, a_src, a_dst, N);
  stats_kernel<<<wblk, 256, 0, stream>>>(a_src, a_dst, row_ptr, csr, p0a, p1a, invS, N);
  gather_slices2<<<sblk, 256, 0, stream>>>(Hs, row_ptr, csr, p0a, p1a, Hagg, N);
  epilogue_kernel<<<eblk, 256, 0, stream>>>(Hagg, invS, b1, buf, N);
  // ---- layer 2 (K=64) ----
  gemm_att<64><<<gblk, 256, 0, stream>>>(buf, W2, as2, ad2, Hs, a_src, a_dst, N);
  stats_kernel<<<wblk, 256, 0, stream>>>(a_src, a_dst, row_ptr, csr, p0a, p1a, invS, N);
  gather_slices2<<<sblk, 256, 0, stream>>>(Hs, row_ptr, csr, p0a, p1a, Hagg, N);
  epilogue_kernel<<<eblk, 256, 0, stream>>>(Hagg, invS, b2, buf, N);
  // ---- layer 3 (K=64) ----
  gemm_att<64><<<gblk, 256, 0, stream>>>(buf, W3, as3, ad3, Hs, a_src, a_dst, N);
  stats_kernel<<<wblk, 256, 0, stream>>>(a_src, a_dst, row_ptr, csr, p0a, p1a, invS, N);
  gather_slices2<<<sblk, 256, 0, stream>>>(Hs, row_ptr, csr, p0a, p1a, Hagg, N);
  epilogue_kernel<<<eblk, 256, 0, stream>>>(Hagg, invS, b3, buf, N);

  // ---- pool + linear ----
  pool_kernel<<<wblk, 256, 0, stream>>>(buf, lw, batch, gsum, gcnt, N);
  finalize_kernel<<<(G + 255) / 256, 256, 0, stream>>>(gsum, gcnt, lb, out, G);
}

// Round 8
// 481.698 us; speedup vs baseline: 1.6118x; 1.6118x over previous
//
#include <hip/hip_runtime.h>
#include <math.h>

// GAT 3-layer: N=50000 nodes, E=800000 edges (+N self loops), HEADS=2, HID=64.
// R8: R6 + manual 8-deep software pipeline in the gather loop. R6/R7 counters
// showed the shfl->load address chain serialized edges (~1 load in flight per
// wave, ~840 cyc/edge). Now: batch 24 shfls -> 8 independent float2 loads ->
// 16 fmas per group, compile-time unrolled. Tail lanes have p=0, s=0 (row 0
// stays L1-hot), so no special-casing.

__device__ __forceinline__ float lrelu(float v) { return v > 0.f ? v : 0.2f * v; }

__device__ __forceinline__ float wave_sum(float v) {
  for (int off = 32; off; off >>= 1) v += __shfl_xor(v, off, 64);
  return v;
}
__device__ __forceinline__ float wave_max(float v) {
  for (int off = 32; off; off >>= 1) v = fmaxf(v, __shfl_xor(v, off, 64));
  return v;
}

__global__ void init_kernel(int* __restrict__ deg, float* __restrict__ gsum,
                            int* __restrict__ gcnt, int n, int g) {
  int i = blockIdx.x * blockDim.x + threadIdx.x;
  if (i < n) deg[i] = 1;                 // self loop
  if (i < g) { gsum[i] = 0.f; gcnt[i] = 0; }
}

__global__ void count_kernel(const int* __restrict__ ei, int* __restrict__ deg, int e) {
  int i = blockIdx.x * blockDim.x + threadIdx.x;
  if (i < e) atomicAdd(&deg[ei[e + i]], 1);   // dst row of edge_index
}

// ---- hierarchical exclusive scan over deg[0..n) ----
__global__ void scan_blocks(const int* __restrict__ deg, int* __restrict__ row_ptr,
                            int* __restrict__ btot, int n) {
  __shared__ int sm[256];
  int i = blockIdx.x * 256 + threadIdx.x;
  int v = (i < n) ? deg[i] : 0;
  sm[threadIdx.x] = v;
  __syncthreads();
  for (int off = 1; off < 256; off <<= 1) {
    int t = (threadIdx.x >= off) ? sm[threadIdx.x - off] : 0;
    __syncthreads();
    sm[threadIdx.x] += t;
    __syncthreads();
  }
  if (i < n) row_ptr[i] = sm[threadIdx.x] - v;   // exclusive within block
  if (threadIdx.x == 255) btot[blockIdx.x] = sm[255];
}

__global__ void scan_totals(int* __restrict__ btot, int nb) {  // nb <= 256
  __shared__ int sm[256];
  int v = (threadIdx.x < nb) ? btot[threadIdx.x] : 0;
  sm[threadIdx.x] = v;
  __syncthreads();
  for (int off = 1; off < 256; off <<= 1) {
    int t = (threadIdx.x >= off) ? sm[threadIdx.x - off] : 0;
    __syncthreads();
    sm[threadIdx.x] += t;
    __syncthreads();
  }
  if (threadIdx.x < nb) btot[threadIdx.x] = sm[threadIdx.x] - v;  // exclusive
}

__global__ void scan_add(int* __restrict__ row_ptr, int* __restrict__ cursor,
                         const int* __restrict__ btot, int n, int total) {
  int i = blockIdx.x * 256 + threadIdx.x;
  if (i < n) {
    int v = row_ptr[i] + btot[blockIdx.x];
    row_ptr[i] = v;
    cursor[i] = v;
  }
  if (i == 0) row_ptr[n] = total;
}

__global__ void scatter_kernel(const int* __restrict__ ei, int* __restrict__ cursor,
                               int* __restrict__ csr_src, int n, int e) {
  int i = blockIdx.x * blockDim.x + threadIdx.x;
  if (i < n) {                               // self loop
    int p = atomicAdd(&cursor[i], 1);
    csr_src[p] = i;
  } else if (i < n + e) {
    int j = i - n;
    int s = ei[j];
    int d = ei[e + j];
    int p = atomicAdd(&cursor[d], 1);
    csr_src[p] = s;
  }
}

// Tiled gemm + fused attention reduce.
// 64-row x 128-col block, 256 threads. cgrp = tid&31 -> cols [cgrp*4,+4);
// rg = tid>>5 -> rows [rg*8,+8). X tile in LDS (pad K+1). W from global
// (L1-hot). Epilogue: a_src/a_dst per (row,head) via 16-lane shfl reduce.
template <int K>
__global__ __launch_bounds__(256) void gemm_att(const float* __restrict__ X,
                                                const float* __restrict__ W,
                                                const float* __restrict__ asw,
                                                const float* __restrict__ adw,
                                                float* __restrict__ H,
                                                float* __restrict__ a_src,
                                                float* __restrict__ a_dst, int N) {
  __shared__ float Xs[64 * (K + 1)];
  int tid = threadIdx.x;
  int row0 = blockIdx.x * 64;

  for (int idx = tid; idx < 64 * K; idx += 256) {
    int r = idx / K;
    int k = idx - r * K;
    int gr = row0 + r;
    if (gr >= N) gr = N - 1;          // clamp pad rows (stores are guarded)
    Xs[r * (K + 1) + k] = X[(size_t)gr * K + k];
  }
  __syncthreads();

  int cgrp = tid & 31;
  int c0 = cgrp * 4;
  int rg = tid >> 5;
  const float* wp = W + c0;
  float acc[8][4] = {};

#pragma unroll 4
  for (int k = 0; k < K; ++k) {
    float4 w4 = *(const float4*)(wp + k * 128);
#pragma unroll
    for (int j = 0; j < 8; ++j) {
      float xv = Xs[(rg * 8 + j) * (K + 1) + k];
      acc[j][0] = fmaf(xv, w4.x, acc[j][0]);
      acc[j][1] = fmaf(xv, w4.y, acc[j][1]);
      acc[j][2] = fmaf(xv, w4.z, acc[j][2]);
      acc[j][3] = fmaf(xv, w4.w, acc[j][3]);
    }
  }

  float4 aw = *(const float4*)(asw + c0);
  float4 dw = *(const float4*)(adw + c0);
#pragma unroll
  for (int j = 0; j < 8; ++j) {
    int r = row0 + rg * 8 + j;
    float sp = acc[j][0] * aw.x + acc[j][1] * aw.y + acc[j][2] * aw.z + acc[j][3] * aw.w;
    float dp = acc[j][0] * dw.x + acc[j][1] * dw.y + acc[j][2] * dw.z + acc[j][3] * dw.w;
#pragma unroll
    for (int off = 1; off < 16; off <<= 1) {
      sp += __shfl_xor(sp, off, 64);
      dp += __shfl_xor(dp, off, 64);
    }
    if (r < N) {
      float4 v = make_float4(acc[j][0], acc[j][1], acc[j][2], acc[j][3]);
      *(float4*)(H + (size_t)r * 128 + c0) = v;
      if ((cgrp & 15) == 0) {
        int head = cgrp >> 4;
        a_src[r * 2 + head] = sp;
        a_dst[r * 2 + head] = dp;
      }
    }
  }
}

// Fused softmax + aggregate. Wave per dst node.
// Softmax: lane j = edge j (coalesced csr, 64-wide a_src gather, shfl
// max/sum). Gather: manual 8-deep pipeline — batch shfls, 8 independent
// 512B loads in flight, then fmas.
__device__ __forceinline__ void gather8(const float* __restrict__ H, int lane,
                                        bool hi, int s, float p0, float p1,
                                        int cnt, float& ax, float& ay) {
  for (int t = 0; t < cnt; t += 8) {
    int st[8];
    float q0[8], q1[8];
#pragma unroll
    for (int k = 0; k < 8; ++k) {        // t+k <= 63 always (t<=56)
      st[k] = __shfl(s, t + k, 64);
      q0[k] = __shfl(p0, t + k, 64);
      q1[k] = __shfl(p1, t + k, 64);
    }
    float2 h[8];
#pragma unroll
    for (int k = 0; k < 8; ++k)
      h[k] = *(const float2*)(H + (size_t)st[k] * 128 + (lane << 1));
#pragma unroll
    for (int k = 0; k < 8; ++k) {
      float pl = hi ? q1[k] : q0[k];
      ax = fmaf(h[k].x, pl, ax);
      ay = fmaf(h[k].y, pl, ay);
    }
  }
}

__global__ __launch_bounds__(256) void aggregate_fused(
    const float* __restrict__ H, const float* __restrict__ a_src,
    const float* __restrict__ a_dst, const float* __restrict__ bias,
    const int* __restrict__ row_ptr, const int* __restrict__ csr,
    float* __restrict__ out, int N) {
  int wid = blockIdx.x * (blockDim.x >> 6) + (threadIdx.x >> 6);
  if (wid >= N) return;
  int lane = threadIdx.x & 63;
  bool hi = lane >= 32;
  int beg = row_ptr[wid], end = row_ptr[wid + 1];
  float2 ad = ((const float2*)a_dst)[wid];
  float ax = 0.f, ay = 0.f;
  float inv0, inv1;

  if (end - beg <= 64) {
    // ---- fast path: single chunk ----
    int j = beg + lane;
    bool valid = j < end;
    int s = valid ? csr[j] : 0;
    float2 as = ((const float2*)a_src)[s];
    float e0 = valid ? lrelu(as.x + ad.x) : -1e30f;
    float e1 = valid ? lrelu(as.y + ad.y) : -1e30f;
    float m0 = wave_max(e0);
    float m1 = wave_max(e1);
    float p0 = __expf(e0 - m0);   // 0 for invalid lanes
    float p1 = __expf(e1 - m1);
    if (!valid) s = 0;            // safe row (stays L1-hot)
    inv0 = 1.f / fmaxf(wave_sum(valid ? p0 : 0.f), 1e-16f);
    inv1 = 1.f / fmaxf(wave_sum(valid ? p1 : 0.f), 1e-16f);
    gather8(H, lane, hi, s, p0, p1, end - beg, ax, ay);
  } else {
    // ---- generic path: online softmax across 64-edge chunks ----
    float m0 = -1e30f, m1 = -1e30f, s0 = 0.f, s1 = 0.f;
    for (int base = beg; base < end; base += 64) {
      int j = base + lane;
      bool valid = j < end;
      int s = valid ? csr[j] : 0;
      float2 as = ((const float2*)a_src)[s];
      float e0 = valid ? lrelu(as.x + ad.x) : -1e30f;
      float e1 = valid ? lrelu(as.y + ad.y) : -1e30f;
      float nm0 = fmaxf(m0, wave_max(e0));
      float nm1 = fmaxf(m1, wave_max(e1));
      s0 = s0 * __expf(m0 - nm0) + wave_sum(valid ? __expf(e0 - nm0) : 0.f);
      s1 = s1 * __expf(m1 - nm1) + wave_sum(valid ? __expf(e1 - nm1) : 0.f);
      m0 = nm0; m1 = nm1;
    }
    inv0 = 1.f / fmaxf(s0, 1e-16f);
    inv1 = 1.f / fmaxf(s1, 1e-16f);
    for (int base = beg; base < end; base += 64) {
      int j = base + lane;
      bool valid = j < end;
      int s = valid ? csr[j] : 0;
      float2 as = ((const float2*)a_src)[s];
      float e0 = valid ? lrelu(as.x + ad.x) : -1e30f;
      float e1 = valid ? lrelu(as.y + ad.y) : -1e30f;
      float p0 = __expf(e0 - m0);
      float p1 = __expf(e1 - m1);
      int cnt = end - base;
      if (cnt > 64) cnt = 64;
      gather8(H, lane, hi, s, p0, p1, cnt, ax, ay);
    }
  }

  float il = hi ? inv1 : inv0;
  ax *= il;
  ay *= il;
  float ox = 0.5f * (ax + __shfl_xor(ax, 32, 64));
  float oy = 0.5f * (ay + __shfl_xor(ay, 32, 64));
  if (lane < 32) {
    int c = lane * 2;
    float v0 = ox + bias[c];
    float v1 = oy + bias[c + 1];
    v0 = v0 > 0.f ? v0 : 0.f;
    v1 = v1 > 0.f ? v1 : 0.f;
    *(float2*)(out + (size_t)wid * 64 + c) = make_float2(v0, v1);
  }
}

// per-node dot with lin_w (linear commutes past the mean), atomic per-graph
__global__ void pool_kernel(const float* __restrict__ X, const float* __restrict__ lw,
                            const int* __restrict__ batch, float* __restrict__ gsum,
                            int* __restrict__ gcnt, int N) {
  int wid = blockIdx.x * (blockDim.x >> 6) + (threadIdx.x >> 6);
  if (wid >= N) return;
  int lane = threadIdx.x & 63;
  float v = X[(size_t)wid * 64 + lane] * lw[lane];
  v = wave_sum(v);
  if (lane == 0) {
    int g = batch[wid];
    atomicAdd(&gsum[g], v);
    atomicAdd(&gcnt[g], 1);
  }
}

__global__ void finalize_kernel(const float* __restrict__ gsum, const int* __restrict__ gcnt,
                                const float* __restrict__ lb, float* __restrict__ out, int G) {
  int g = blockIdx.x * blockDim.x + threadIdx.x;
  if (g < G) out[g] = gsum[g] / fmaxf((float)gcnt[g], 1.f) + lb[0];
}

extern "C" void kernel_launch(void* const* d_in, const int* in_sizes, int n_in,
                              void* d_out, int out_size, void* d_ws, size_t ws_size,
                              hipStream_t stream) {
  const float* x   = (const float*)d_in[0];
  const int* ei    = (const int*)d_in[1];
  const int* batch = (const int*)d_in[2];
  const float* W1  = (const float*)d_in[3];
  const float* as1 = (const float*)d_in[4];
  const float* ad1 = (const float*)d_in[5];
  const float* b1  = (const float*)d_in[6];
  const float* W2  = (const float*)d_in[7];
  const float* as2 = (const float*)d_in[8];
  const float* ad2 = (const float*)d_in[9];
  const float* b2  = (const float*)d_in[10];
  const float* W3  = (const float*)d_in[11];
  const float* as3 = (const float*)d_in[12];
  const float* ad3 = (const float*)d_in[13];
  const float* b3  = (const float*)d_in[14];
  const float* lw  = (const float*)d_in[15];
  const float* lb  = (const float*)d_in[16];
  float* out = (float*)d_out;

  const int N = in_sizes[0] / 128;   // 50000
  const int E = in_sizes[1] / 2;     // 800000
  const int ET = N + E;              // with self loops
  const int G = out_size;            // 2500
  const int NB = (N + 255) / 256;    // scan blocks (196 <= 256)

  char* p = (char*)d_ws;
  auto take = [&](size_t bytes) {
    char* r = p;
    p += (bytes + 255) & ~(size_t)255;
    return r;
  };
  int* deg      = (int*)take((size_t)N * 4);
  int* row_ptr  = (int*)take((size_t)(N + 1) * 4);
  int* cursor   = (int*)take((size_t)N * 4);
  int* btot     = (int*)take((size_t)NB * 4);
  int* csr      = (int*)take((size_t)ET * 4);
  float* H      = (float*)take((size_t)N * 128 * 4);
  float* a_src  = (float*)take((size_t)N * 2 * 4);
  float* a_dst  = (float*)take((size_t)N * 2 * 4);
  float* bufA   = (float*)take((size_t)N * 64 * 4);
  float* bufB   = (float*)take((size_t)N * 64 * 4);
  float* gsum   = (float*)take((size_t)G * 4);
  int* gcnt     = (int*)take((size_t)G * 4);
  (void)ws_size; (void)n_in;

  // ---- CSR build (dst-sorted, with self loops) ----
  init_kernel<<<(N + 255) / 256, 256, 0, stream>>>(deg, gsum, gcnt, N, G);
  count_kernel<<<(E + 255) / 256, 256, 0, stream>>>(ei, deg, E);
  scan_blocks<<<NB, 256, 0, stream>>>(deg, row_ptr, btot, N);
  scan_totals<<<1, 256, 0, stream>>>(btot, NB);
  scan_add<<<NB, 256, 0, stream>>>(row_ptr, cursor, btot, N, ET);
  scatter_kernel<<<(ET + 255) / 256, 256, 0, stream>>>(ei, cursor, csr, N, E);

  const int gblk = (N + 63) / 64;
  const int wblk = (N + 3) / 4;

  // ---- layer 1 (K=128) ----
  gemm_att<128><<<gblk, 256, 0, stream>>>(x, W1, as1, ad1, H, a_src, a_dst, N);
  aggregate_fused<<<wblk, 256, 0, stream>>>(H, a_src, a_dst, b1, row_ptr, csr, bufA, N);
  // ---- layer 2 (K=64) ----
  gemm_att<64><<<gblk, 256, 0, stream>>>(bufA, W2, as2, ad2, H, a_src, a_dst, N);
  aggregate_fused<<<wblk, 256, 0, stream>>>(H, a_src, a_dst, b2, row_ptr, csr, bufB, N);
  // ---- layer 3 (K=64) ----
  gemm_att<64><<<gblk, 256, 0, stream>>>(bufB, W3, as3, ad3, H, a_src, a_dst, N);
  aggregate_fused<<<wblk, 256, 0, stream>>>(H, a_src, a_dst, b3, row_ptr, csr, bufA, N);

  // ---- pool + linear ----
  pool_kernel<<<wblk, 256, 0, stream>>>(bufA, lw, batch, gsum, gcnt, N);
  finalize_kernel<<<(G + 255) / 256, 256, 0, stream>>>(gsum, gcnt, lb, out, G);
}